// Round 5
// baseline (641.766 us; speedup 1.0000x reference)
//
#include <hip/hip_runtime.h>

#define D 64          // D_IN == D_OUT
#define D_EDGE 16
#define NEG 0.01f

__device__ __forceinline__ float leaky(float v) { return v > 0.f ? v : NEG * v; }

// ---------------- Kernel 1: per-node precompute ----------------
//   x_t[n] = x[n] @ W2.T          (W2 [64][64])
//   A[n]   = x[n] @ W1[:, :64].T  (W1 [64][80], cols 0..63)
//   r[n]   = sum_j leaky(x[n][j]) * attn[64+j]
__global__ __launch_bounds__(256) void node_kernel(
    const float* __restrict__ x, const float* __restrict__ W1,
    const float* __restrict__ W2, const float* __restrict__ attn,
    float* __restrict__ A, float* __restrict__ xt, float* __restrict__ r, int N_)
{
    __shared__ float w2s[64 * 64];
    __shared__ float w1s[64 * 64];
    __shared__ float ah[64];
    for (int i = threadIdx.x; i < 64 * 64; i += 256) {
        w2s[i] = W2[i];
        int k = i >> 6, j = i & 63;
        w1s[i] = W1[k * 80 + j];
    }
    if (threadIdx.x < 64) ah[threadIdx.x] = attn[64 + threadIdx.x];
    __syncthreads();

    int n = blockIdx.x * 256 + threadIdx.x;
    if (n >= N_) return;

    const float4* x4 = (const float4*)(x + (size_t)n * D);
    float4 xr[16];
#pragma unroll
    for (int i = 0; i < 16; i++) xr[i] = x4[i];

    const float4* w2s4 = (const float4*)w2s;
    const float4* w1s4 = (const float4*)w1s;
    for (int k = 0; k < 64; k++) {
        float a = 0.f, b = 0.f;
#pragma unroll
        for (int j = 0; j < 16; j++) {
            float4 w = w2s4[k * 16 + j];
            a += xr[j].x * w.x + xr[j].y * w.y + xr[j].z * w.z + xr[j].w * w.w;
            float4 u = w1s4[k * 16 + j];
            b += xr[j].x * u.x + xr[j].y * u.y + xr[j].z * u.z + xr[j].w * u.w;
        }
        xt[(size_t)n * D + k] = a;
        A[(size_t)n * D + k]  = b;
    }

    float rr = 0.f;
#pragma unroll
    for (int j = 0; j < 16; j++) {
        rr += leaky(xr[j].x) * ah[4 * j + 0];
        rr += leaky(xr[j].y) * ah[4 * j + 1];
        rr += leaky(xr[j].z) * ah[4 * j + 2];
        rr += leaky(xr[j].w) * ah[4 * j + 3];
    }
    r[n] = rr;
}

// ---------------- Kernel 2: fused edge kernel, 4 edges / wave-iter ---------
// Half-wave owns one edge of each pair; lane l: half = l>>5, k0 = (l&31)*2.
// Two pairs (4 edges) per iteration -> 4 independent gather/reduce chains.
#define EDOTQ(eptr, g0, g1) {                                                 \
    float4 q0 = eptr[0], q1 = eptr[1], q2 = eptr[2], q3 = eptr[3];            \
    g0 = q0.x*wa0.x + q0.y*wa0.y + q0.z*wa0.z + q0.w*wa0.w                    \
       + q1.x*wa1.x + q1.y*wa1.y + q1.z*wa1.z + q1.w*wa1.w                    \
       + q2.x*wa2.x + q2.y*wa2.y + q2.z*wa2.z + q2.w*wa2.w                    \
       + q3.x*wa3.x + q3.y*wa3.y + q3.z*wa3.z + q3.w*wa3.w;                   \
    g1 = q0.x*wb0.x + q0.y*wb0.y + q0.z*wb0.z + q0.w*wb0.w                    \
       + q1.x*wb1.x + q1.y*wb1.y + q1.z*wb1.z + q1.w*wb1.w                    \
       + q2.x*wb2.x + q2.y*wb2.y + q2.z*wb2.z + q2.w*wb2.w                    \
       + q3.x*wb3.x + q3.y*wb3.y + q3.z*wb3.z + q3.w*wb3.w; }

__global__ __launch_bounds__(256) void edge_kernel(
    const float* __restrict__ edge_attr, const int* __restrict__ src,
    const int* __restrict__ dst, const float* __restrict__ W1,
    const float* __restrict__ attn,
    const float* __restrict__ A, const float* __restrict__ xt,
    const float* __restrict__ r,
    float* __restrict__ out, float* __restrict__ denom,
    int E_, int chunk)
{
    const int lane = threadIdx.x & 63;
    const int half = lane >> 5;
    const int k0   = (lane & 31) * 2;

    // this lane's two W1b rows (cols 64..79) + attn weights
    const float4* w1p = (const float4*)(W1 + k0 * 80 + 64);
    float4 wa0 = w1p[0], wa1 = w1p[1], wa2 = w1p[2], wa3 = w1p[3];
    const float4* w1q = (const float4*)(W1 + (k0 + 1) * 80 + 64);
    float4 wb0 = w1q[0], wb1 = w1q[1], wb2 = w1q[2], wb3 = w1q[3];
    float ak0 = attn[k0], ak1 = attn[k0 + 1];

    const int wave   = blockIdx.x * 4 + (threadIdx.x >> 6);
    const int nquads = E_ >> 2;
    int q  = wave * chunk;
    int qe = q + chunk; if (qe > nquads) qe = nquads;

    for (; q < qe; q++) {
        const int e0 = q * 4;
        int4 ss = *(const int4*)(src + e0);
        int4 dd = *(const int4*)(dst + e0);

        // 4 independent A-row gathers in flight (2 per instr, one per half)
        int sA = half ? ss.y : ss.x;
        int sB = half ? ss.w : ss.z;
        float2 aA = *(const float2*)(A + (size_t)sA * D + k0);
        float2 aB = *(const float2*)(A + (size_t)sB * D + k0);

        const float4* eaA = (const float4*)(edge_attr + (size_t)(e0 + half) * D_EDGE);
        const float4* eaB = (const float4*)(edge_attr + (size_t)(e0 + 2 + half) * D_EDGE);

        float gA0, gA1, gB0, gB1;
        EDOTQ(eaA, gA0, gA1)
        EDOTQ(eaB, gB0, gB1)

        float vA = leaky(aA.x + gA0) * ak0 + leaky(aA.y + gA1) * ak1;
        float vB = leaky(aB.x + gB0) * ak0 + leaky(aB.y + gB1) * ak1;

        // two interleaved butterflies within 32-lane halves
#pragma unroll
        for (int off = 16; off > 0; off >>= 1) {
            vA += __shfl_xor(vA, off, 64);
            vB += __shfl_xor(vB, off, 64);
        }
        float voA = __shfl_xor(vA, 32, 64);
        float voB = __shfl_xor(vB, 32, 64);
        float v0 = half ? voA : vA;   // edge e0 logit (all lanes)
        float v1 = half ? vA : voA;   // edge e0+1
        float v2 = half ? voB : vB;   // edge e0+2
        float v3 = half ? vB : voB;   // edge e0+3

        float p0 = __expf(v0 + r[dd.x]);
        float p1 = __expf(v1 + r[dd.y]);
        float p2 = __expf(v2 + r[dd.z]);
        float p3 = __expf(v3 + r[dd.w]);

        // aggregation: full wave per edge, lane = output channel; 4 gathers in flight
        float m0 = xt[(size_t)ss.x * D + lane];
        float m1 = xt[(size_t)ss.y * D + lane];
        float m2 = xt[(size_t)ss.z * D + lane];
        float m3 = xt[(size_t)ss.w * D + lane];
        atomicAdd(out + (size_t)dd.x * D + lane, p0 * m0);
        atomicAdd(out + (size_t)dd.y * D + lane, p1 * m1);
        atomicAdd(out + (size_t)dd.z * D + lane, p2 * m2);
        atomicAdd(out + (size_t)dd.w * D + lane, p3 * m3);
        if      (lane == 0)  atomicAdd(denom + dd.x, p0);
        else if (lane == 16) atomicAdd(denom + dd.y, p1);
        else if (lane == 32) atomicAdd(denom + dd.z, p2);
        else if (lane == 48) atomicAdd(denom + dd.w, p3);
    }

    // tail: E_ % 4 leftover edges, wave 0 only
    if (wave == 0) {
        for (int e = nquads * 4; e < E_; e++) {
            int s = src[e], d = dst[e];
            float2 a2 = *(const float2*)(A + (size_t)s * D + k0);
            const float4* eap = (const float4*)(edge_attr + (size_t)e * D_EDGE);
            float g0, g1;
            EDOTQ(eap, g0, g1)
            float v = leaky(a2.x + g0) * ak0 + leaky(a2.y + g1) * ak1;
#pragma unroll
            for (int off = 32; off > 0; off >>= 1) v += __shfl_xor(v, off, 64);
            float p = __expf(v + r[d]);
            atomicAdd(out + (size_t)d * D + lane, p * xt[(size_t)s * D + lane]);
            if (lane == 0) atomicAdd(denom + d, p);
        }
    }
}

// ---------------- Kernel 3: normalize + bias ----------------
__global__ __launch_bounds__(256) void fin_kernel(
    float* __restrict__ out, const float* __restrict__ denom,
    const float* __restrict__ bias, int total)
{
    int i = blockIdx.x * 256 + threadIdx.x;
    if (i >= total) return;
    int n = i >> 6, k = i & 63;
    float dn = denom[n];
    float sc = dn > 0.f ? 1.f / dn : 0.f;
    out[i] = fmaf(out[i], sc, bias[k]);
}

extern "C" void kernel_launch(void* const* d_in, const int* in_sizes, int n_in,
                              void* d_out, int out_size, void* d_ws, size_t ws_size,
                              hipStream_t stream)
{
    const float* x         = (const float*)d_in[0];
    const float* edge_attr = (const float*)d_in[1];
    const int*   src       = (const int*)d_in[2];
    const int*   dst       = (const int*)d_in[3];
    const float* W1        = (const float*)d_in[4];
    const float* W2        = (const float*)d_in[5];
    const float* attn      = (const float*)d_in[6];
    const float* bias      = (const float*)d_in[7];
    float* out = (float*)d_out;

    const int N_ = in_sizes[0] / D;   // 100000
    const int E_ = in_sizes[2];       // 1280000

    // workspace (fp32): A[N*64] | xt[N*64] | r[N] | denom[N]
    float* A     = (float*)d_ws;
    float* xt    = A  + (size_t)N_ * D;
    float* r     = xt + (size_t)N_ * D;
    float* denom = r  + N_;

    hipMemsetAsync(out,   0, (size_t)out_size * sizeof(float), stream);
    hipMemsetAsync(denom, 0, (size_t)N_ * sizeof(float), stream);

    node_kernel<<<(N_ + 255) / 256, 256, 0, stream>>>(x, W1, W2, attn, A, xt, r, N_);

    const int eBlocks = 8192;
    const int nwaves  = eBlocks * 4;
    const int nquads  = E_ >> 2;
    const int chunk   = (nquads + nwaves - 1) / nwaves;   // contiguous quads per wave
    edge_kernel<<<eBlocks, 256, 0, stream>>>(edge_attr, src, dst, W1, attn,
                                             A, xt, r, out, denom, E_, chunk);

    fin_kernel<<<((size_t)N_ * D + 255) / 256, 256, 0, stream>>>(out, denom, bias, N_ * D);
}

// Round 6
// 549.395 us; speedup vs baseline: 1.1681x; 1.1681x over previous
//
#include <hip/hip_runtime.h>

#define D 64          // D_IN == D_OUT
#define D_EDGE 16
#define NEG 0.01f

typedef unsigned int  uint32;
typedef unsigned short ushort16;

__device__ __forceinline__ float leaky(float v) { return v > 0.f ? v : NEG * v; }

// fp32 -> bf16 (round-to-nearest-even), and back (exact)
__device__ __forceinline__ ushort16 f2bf(float f) {
    uint32 b = __float_as_uint(f);
    uint32 r = b + 0x7fffu + ((b >> 16) & 1u);
    return (ushort16)(r >> 16);
}
__device__ __forceinline__ float bf2f(ushort16 u) {
    return __uint_as_float(((uint32)u) << 16);
}

// ---------------- Kernel 1: per-node precompute (quarter-split) ----------------
//   4 threads per node; thread quarter q owns output channels [q*16, q*16+16).
//   xt[n] (bf16) = x[n] @ W2.T ; A[n] (bf16) = x[n] @ W1[:, :64].T
//   r[n] = sum_j leaky(x[n][j]) * attn[64+j]   (computed by q==0 threads)
__global__ __launch_bounds__(256) void node_kernel(
    const float* __restrict__ x, const float* __restrict__ W1,
    const float* __restrict__ W2, const float* __restrict__ attn,
    ushort16* __restrict__ Abf, ushort16* __restrict__ xtb,
    float* __restrict__ r, int N_)
{
    __shared__ float w2s[64 * 64];
    __shared__ float w1s[64 * 64];
    __shared__ float ah[64];
    for (int i = threadIdx.x; i < 64 * 64; i += 256) {
        w2s[i] = W2[i];
        int k = i >> 6, j = i & 63;
        w1s[i] = W1[k * 80 + j];
    }
    if (threadIdx.x < 64) ah[threadIdx.x] = attn[64 + threadIdx.x];
    __syncthreads();

    const int lane = threadIdx.x & 63;
    const int q    = threadIdx.x >> 6;          // output quarter 0..3
    const int n    = blockIdx.x * 64 + lane;
    if (n >= N_) return;

    const float4* x4 = (const float4*)(x + (size_t)n * D);
    float4 xr[16];
#pragma unroll
    for (int i = 0; i < 16; i++) xr[i] = x4[i];

    const float4* w2s4 = (const float4*)w2s;
    const float4* w1s4 = (const float4*)w1s;

    uint32* Au = (uint32*)Abf;   // packed bf16x2, dword index = n*32 + k/2
    uint32* Xu = (uint32*)xtb;

    float a_prev = 0.f, b_prev = 0.f;
#pragma unroll
    for (int kk = 0; kk < 16; kk++) {
        const int k = q * 16 + kk;
        float a = 0.f, b = 0.f;
#pragma unroll
        for (int j = 0; j < 16; j++) {
            float4 w = w2s4[k * 16 + j];
            a += xr[j].x * w.x + xr[j].y * w.y + xr[j].z * w.z + xr[j].w * w.w;
            float4 u = w1s4[k * 16 + j];
            b += xr[j].x * u.x + xr[j].y * u.y + xr[j].z * u.z + xr[j].w * u.w;
        }
        if (kk & 1) {
            // pack (even, odd) -> low, high
            Xu[(size_t)n * 32 + (k >> 1)] = (uint32)f2bf(a_prev) | ((uint32)f2bf(a) << 16);
            Au[(size_t)n * 32 + (k >> 1)] = (uint32)f2bf(b_prev) | ((uint32)f2bf(b) << 16);
        } else {
            a_prev = a; b_prev = b;
        }
    }

    if (q == 0) {
        float rr = 0.f;
#pragma unroll
        for (int j = 0; j < 16; j++) {
            rr += leaky(xr[j].x) * ah[4 * j + 0];
            rr += leaky(xr[j].y) * ah[4 * j + 1];
            rr += leaky(xr[j].z) * ah[4 * j + 2];
            rr += leaky(xr[j].w) * ah[4 * j + 3];
        }
        r[n] = rr;
    }
}

// ---------------- Kernel 2: fused edge kernel, half-wave per edge ----------
// Wave handles 2 edges (e0 = 2*pair, e1 = e0+1). Lane l: half = l>>5,
// k0 = (l&31)*2 — lane owns logits-k {k0,k0+1} of its half's edge.
// A and xt are bf16 (halved gather traffic); math + atomics stay fp32.
__global__ __launch_bounds__(256) void edge_kernel(
    const float* __restrict__ edge_attr, const int* __restrict__ src,
    const int* __restrict__ dst, const float* __restrict__ W1,
    const float* __restrict__ attn,
    const ushort16* __restrict__ Abf, const ushort16* __restrict__ xtb,
    const float* __restrict__ r,
    float* __restrict__ out, float* __restrict__ denom,
    int E_, int chunk)
{
    const int lane = threadIdx.x & 63;
    const int half = lane >> 5;
    const int k0   = (lane & 31) * 2;

    // this lane's two W1b rows (cols 64..79) + attn weights
    const float4* w1p = (const float4*)(W1 + k0 * 80 + 64);
    float4 wa0 = w1p[0], wa1 = w1p[1], wa2 = w1p[2], wa3 = w1p[3];
    const float4* w1q = (const float4*)(W1 + (k0 + 1) * 80 + 64);
    float4 wb0 = w1q[0], wb1 = w1q[1], wb2 = w1q[2], wb3 = w1q[3];
    float ak0 = attn[k0], ak1 = attn[k0 + 1];

    const uint32* Au = (const uint32*)Abf;   // dword idx = s*32 + k0/2

    const int wave   = blockIdx.x * 4 + (threadIdx.x >> 6);
    const int npairs = E_ >> 1;
    int pr  = wave * chunk;
    int pe  = pr + chunk; if (pe > npairs) pe = npairs;

    for (; pr < pe; pr++) {
        const int e0 = pr * 2;
        int2 ss = *(const int2*)(src + e0);
        int2 dd = *(const int2*)(dst + e0);

        // half-specific src row: one packed bf16x2 dword per lane (128B/edge)
        int s_h = half ? ss.y : ss.x;
        uint32 av = Au[(size_t)s_h * 32 + (lane & 31)];
        float a0 = bf2f((ushort16)(av & 0xffffu));
        float a1 = bf2f((ushort16)(av >> 16));

        // half-specific edge_attr row (two rows contiguous 128B)
        const float4* eap = (const float4*)(edge_attr + (size_t)(e0 + half) * D_EDGE);
        float4 q0 = eap[0], q1 = eap[1], q2 = eap[2], q3 = eap[3];

        float g0 = q0.x*wa0.x + q0.y*wa0.y + q0.z*wa0.z + q0.w*wa0.w
                 + q1.x*wa1.x + q1.y*wa1.y + q1.z*wa1.z + q1.w*wa1.w
                 + q2.x*wa2.x + q2.y*wa2.y + q2.z*wa2.z + q2.w*wa2.w
                 + q3.x*wa3.x + q3.y*wa3.y + q3.z*wa3.z + q3.w*wa3.w;
        float g1 = q0.x*wb0.x + q0.y*wb0.y + q0.z*wb0.z + q0.w*wb0.w
                 + q1.x*wb1.x + q1.y*wb1.y + q1.z*wb1.z + q1.w*wb1.w
                 + q2.x*wb2.x + q2.y*wb2.y + q2.z*wb2.z + q2.w*wb2.w
                 + q3.x*wb3.x + q3.y*wb3.y + q3.z*wb3.z + q3.w*wb3.w;

        float v = leaky(a0 + g0) * ak0 + leaky(a1 + g1) * ak1;

        // butterfly within each 32-lane half, then cross-half exchange
#pragma unroll
        for (int off = 16; off > 0; off >>= 1) v += __shfl_xor(v, off, 64);
        float vo = __shfl_xor(v, 32, 64);
        float vA = half ? vo : v;
        float vB = half ? v : vo;

        float pA = __expf(vA + r[dd.x]);
        float pB = __expf(vB + r[dd.y]);

        // aggregation: full wave per edge, lane = output channel (bf16 gather)
        float mA = bf2f(xtb[(size_t)ss.x * D + lane]);
        float mB = bf2f(xtb[(size_t)ss.y * D + lane]);
        atomicAdd(out + (size_t)dd.x * D + lane, pA * mA);
        atomicAdd(out + (size_t)dd.y * D + lane, pB * mB);
        if (lane == 0)       atomicAdd(denom + dd.x, pA);
        else if (lane == 32) atomicAdd(denom + dd.y, pB);
    }

    // tail: odd E_ (not the case here, but stay correct)
    if (wave == 0 && (E_ & 1)) {
        int e = E_ - 1;
        int s = src[e], d = dst[e];
        uint32 av = Au[(size_t)s * 32 + (lane & 31)];
        float a0 = bf2f((ushort16)(av & 0xffffu));
        float a1 = bf2f((ushort16)(av >> 16));
        const float4* eap = (const float4*)(edge_attr + (size_t)e * D_EDGE);
        float4 q0 = eap[0], q1 = eap[1], q2 = eap[2], q3 = eap[3];
        float g0 = q0.x*wa0.x + q0.y*wa0.y + q0.z*wa0.z + q0.w*wa0.w
                 + q1.x*wa1.x + q1.y*wa1.y + q1.z*wa1.z + q1.w*wa1.w
                 + q2.x*wa2.x + q2.y*wa2.y + q2.z*wa2.z + q2.w*wa2.w
                 + q3.x*wa3.x + q3.y*wa3.y + q3.z*wa3.z + q3.w*wa3.w;
        float g1 = q0.x*wb0.x + q0.y*wb0.y + q0.z*wb0.z + q0.w*wb0.w
                 + q1.x*wb1.x + q1.y*wb1.y + q1.z*wb1.z + q1.w*wb1.w
                 + q2.x*wb2.x + q2.y*wb2.y + q2.z*wb2.z + q2.w*wb2.w
                 + q3.x*wb3.x + q3.y*wb3.y + q3.z*wb3.z + q3.w*wb3.w;
        float v = leaky(a0 + g0) * ak0 + leaky(a1 + g1) * ak1;
#pragma unroll
        for (int off = 32; off > 0; off >>= 1) v += __shfl_xor(v, off, 64);
        float p = __expf(v + r[d]);
        atomicAdd(out + (size_t)d * D + lane, p * bf2f(xtb[(size_t)s * D + lane]));
        if (lane == 0) atomicAdd(denom + d, p);
    }
}

// ---------------- Kernel 3: normalize + bias ----------------
__global__ __launch_bounds__(256) void fin_kernel(
    float* __restrict__ out, const float* __restrict__ denom,
    const float* __restrict__ bias, int total)
{
    int i = blockIdx.x * 256 + threadIdx.x;
    if (i >= total) return;
    int n = i >> 6, k = i & 63;
    float dn = denom[n];
    float sc = dn > 0.f ? 1.f / dn : 0.f;
    out[i] = fmaf(out[i], sc, bias[k]);
}

extern "C" void kernel_launch(void* const* d_in, const int* in_sizes, int n_in,
                              void* d_out, int out_size, void* d_ws, size_t ws_size,
                              hipStream_t stream)
{
    const float* x         = (const float*)d_in[0];
    const float* edge_attr = (const float*)d_in[1];
    const int*   src       = (const int*)d_in[2];
    const int*   dst       = (const int*)d_in[3];
    const float* W1        = (const float*)d_in[4];
    const float* W2        = (const float*)d_in[5];
    const float* attn      = (const float*)d_in[6];
    const float* bias      = (const float*)d_in[7];
    float* out = (float*)d_out;

    const int N_ = in_sizes[0] / D;   // 100000
    const int E_ = in_sizes[2];       // 1280000

    // workspace: Abf[N*64] bf16 | xtb[N*64] bf16 | r[N] f32 | denom[N] f32
    ushort16* Abf = (ushort16*)d_ws;
    ushort16* xtb = Abf + (size_t)N_ * D;
    float*    r     = (float*)(xtb + (size_t)N_ * D);
    float*    denom = r + N_;

    hipMemsetAsync(out,   0, (size_t)out_size * sizeof(float), stream);
    hipMemsetAsync(denom, 0, (size_t)N_ * sizeof(float), stream);

    node_kernel<<<(N_ + 63) / 64, 256, 0, stream>>>(x, W1, W2, attn, Abf, xtb, r, N_);

    const int eBlocks = 8192;
    const int nwaves  = eBlocks * 4;
    const int npairs  = E_ >> 1;
    const int chunk   = (npairs + nwaves - 1) / nwaves;   // contiguous pairs per wave
    edge_kernel<<<eBlocks, 256, 0, stream>>>(edge_attr, src, dst, W1, attn,
                                             Abf, xtb, r, out, denom, E_, chunk);

    fin_kernel<<<((size_t)N_ * D + 255) / 256, 256, 0, stream>>>(out, denom, bias, N_ * D);
}